// Round 2
// 573.716 us; speedup vs baseline: 1.0037x; 1.0037x over previous
//
#include <hip/hip_runtime.h>
#include <hip/hip_bf16.h>

typedef __attribute__((ext_vector_type(8))) short short8;
typedef __attribute__((ext_vector_type(8))) unsigned short ushort8;
typedef __attribute__((ext_vector_type(4))) float f32x4;
typedef __attribute__((ext_vector_type(2))) unsigned int uint2v;
typedef __attribute__((ext_vector_type(4))) unsigned int uint4v;

#define DN   128
#define DE   64
#define DIN  192
#define HID  256
#define OUTD 128
#define TE   64      // edges per block
#define NT   256     // threads per block (4 waves)
#define MSG_LD 200   // 192 + 8 pad (bf16): row stride 400B, bank-uniform for b128 reads
#define OUT_LD 132   // f32 out tile stride (128 + 4)
#define NMB  (TE / 16)   // m-blocks in the blocked-transposed h tile

static __device__ __forceinline__ unsigned short f2b(float f) {
    unsigned int u = __float_as_uint(f);
    u += 0x7fffu + ((u >> 16) & 1u);
    return (unsigned short)(u >> 16);
}

// packed RNE f32x2 -> bf16x2 (gfx950 native)
static __device__ __forceinline__ unsigned int cvt_pk2(float lo, float hi) {
    unsigned int r;
    asm("v_cvt_pk_bf16_f32 %0, %1, %2" : "=v"(r) : "v"(lo), "v"(hi));
    return r;
}

// hardware transpose-read. Semantics (m156-consistent): the per-lane address
// selects an 8B slot within a 128B-aligned region; the region is a 4x16
// row-major bf16 tile and the lane receives COLUMN (addr mod 128)/8, i.e.
// elems col + j*16 for j=0..3. offset:N is additive in bytes (region-granular
// offsets walk sub-tiles).
template<int OFF>
static __device__ __forceinline__ uint2v tr_read(unsigned addr) {
    uint2v d;
    asm volatile("ds_read_b64_tr_b16 %0, %1 offset:%c2"
                 : "=v"(d) : "v"(addr), "n"(OFF));
    return d;
}

// Fused prep: (a) pack 4 weight mats to bf16 fragment layout Wp[((k/32)*Nc+n)*32+(k%32)],
// (b) histogram dest rows per branch, (c) convert x to bf16.
__global__ __launch_bounds__(256)
void prep_kernel(const float* __restrict__ W1o, const float* __restrict__ W1i,
                 const float* __restrict__ W2o, const float* __restrict__ W2i,
                 unsigned short* __restrict__ W1po, unsigned short* __restrict__ W1pi,
                 unsigned short* __restrict__ W2po, unsigned short* __restrict__ W2pi,
                 const int* __restrict__ ei, int E, int N, int* __restrict__ hist,
                 const float* __restrict__ x, unsigned short* __restrict__ xb) {
    const int S1 = DIN * HID, S2v = HID * OUTD;
    const int PACKN = 2 * S1 + 2 * S2v;
    int idx = blockIdx.x * blockDim.x + threadIdx.x;
    if (idx < PACKN) {
        const float* W; unsigned short* Wp; int Nc, j;
        if      (idx < S1)          { W = W1o; Wp = W1po; Nc = HID;  j = idx; }
        else if (idx < 2*S1)        { W = W1i; Wp = W1pi; Nc = HID;  j = idx - S1; }
        else if (idx < 2*S1 + S2v)  { W = W2o; Wp = W2po; Nc = OUTD; j = idx - 2*S1; }
        else                        { W = W2i; Wp = W2pi; Nc = OUTD; j = idx - 2*S1 - S2v; }
        int k = j / Nc, n = j - k * Nc;
        Wp[(((k >> 5) * Nc + n) << 5) + (k & 31)] = f2b(W[j]);
    } else if (idx < PACKN + E) {
        int e = idx - PACKN;
        int r = ei[e], c = ei[E + e];
        if      (r < c) atomicAdd(&hist[r], 1);
        else if (r > c) atomicAdd(&hist[N + r], 1);
    } else {
        int i = idx - PACKN - E;           // 8 x-floats per thread
        if (i < N * DN / 8) {
            float4 a = reinterpret_cast<const float4*>(x)[i * 2];
            float4 b = reinterpret_cast<const float4*>(x)[i * 2 + 1];
            ushort8 v = { f2b(a.x), f2b(a.y), f2b(a.z), f2b(a.w),
                          f2b(b.x), f2b(b.y), f2b(b.z), f2b(b.w) };
            reinterpret_cast<ushort8*>(xb)[i] = v;
        }
    }
}

// Per-chunk (1024 rows) exclusive scan of one branch's histogram.
__global__ __launch_bounds__(1024)
void scan1_kernel(const int* __restrict__ hist, int* __restrict__ cursor,
                  int* __restrict__ chunkSum, int N, int nch) {
    __shared__ int s_ws[16];
    const int br = blockIdx.x / nch, ch = blockIdx.x - br * nch;
    const int tid = threadIdx.x, lane = tid & 63, wv = tid >> 6;
    const int i = ch * 1024 + tid;
    int v = (i < N) ? hist[(size_t)br * N + i] : 0;
    int incl = v;
    #pragma unroll
    for (int d = 1; d < 64; d <<= 1) {
        int t = __shfl_up(incl, d, 64);
        if (lane >= d) incl += t;
    }
    if (lane == 63) s_ws[wv] = incl;
    __syncthreads();
    if (tid < 16) {
        int w = s_ws[tid];
        int wi = w;
        #pragma unroll
        for (int d = 1; d < 16; d <<= 1) {
            int t = __shfl_up(wi, d, 64);
            if (tid >= d) wi += t;
        }
        s_ws[tid] = wi - w;
    }
    __syncthreads();
    int excl = s_ws[wv] + incl - v;
    if (i < N) cursor[(size_t)br * N + i] = excl;
    if (tid == 1023) chunkSum[br * nch + ch] = excl + v;
}

// Scan chunk sums (nch <= 64 per branch): wave 0 -> branch 0, wave 1 -> branch 1.
__global__ __launch_bounds__(128)
void scan2_kernel(int* __restrict__ chunkSum, int* __restrict__ cnt, int nch) {
    const int br = threadIdx.x >> 6, lane = threadIdx.x & 63;
    int v = (lane < nch) ? chunkSum[br * nch + lane] : 0;
    int incl = v;
    #pragma unroll
    for (int d = 1; d < 64; d <<= 1) {
        int t = __shfl_up(incl, d, 64);
        if (lane >= d) incl += t;
    }
    if (lane < nch) chunkSum[br * nch + lane] = incl - v;
    if (lane == nch - 1) cnt[br] = incl;
}

// Scatter edges to sorted-by-dest-row positions.
__global__ __launch_bounds__(256)
void reorder_kernel(const int* __restrict__ ei, int E, int N, int nch,
                    int* __restrict__ cursor, const int* __restrict__ chunkSum,
                    int* __restrict__ list_out, int* __restrict__ list_in) {
    int e = blockIdx.x * blockDim.x + threadIdx.x;
    if (e >= E) return;
    int r = ei[e], c = ei[E + e];
    if (r == c) return;
    int br = (r < c) ? 0 : 1;
    int p = chunkSum[br * nch + (r >> 10)] + atomicAdd(&cursor[(size_t)br * N + r], 1);
    (br ? list_in : list_out)[p] = e;
}

__global__ __launch_bounds__(NT, 4)
void mlp_scatter_kernel(const unsigned short* __restrict__ xb,
                        const int* __restrict__ ei,
                        const float* __restrict__ ea,
                        const unsigned short* __restrict__ W1p_out,
                        const unsigned short* __restrict__ W1p_in,
                        const float* __restrict__ b1_out,
                        const float* __restrict__ b1_in,
                        const unsigned short* __restrict__ W2p_out,
                        const unsigned short* __restrict__ W2p_in,
                        const float* __restrict__ b2_out,
                        const float* __restrict__ b2_in,
                        const int* __restrict__ list_out,
                        const int* __restrict__ list_in,
                        const int* __restrict__ cnt,
                        float* __restrict__ out,
                        int E) {
    // Union buffer, 33792 B: msg bf16 (64x200=25600B) -> hT blocked bf16 (32768B)
    //                        -> out f32 (64x132=33792B).
    __shared__ __align__(16) unsigned short s_buf[TE * 264];
    __shared__ int s_eid[TE], s_dest[TE], s_col[TE];

    // Device-side branch mapping: no empty half-grid.
    const int c0 = cnt[0], c1 = cnt[1];
    const int nb0 = (c0 + TE - 1) / TE;
    const int branch = (blockIdx.x >= nb0) ? 1 : 0;   // 0 = out-flow, 1 = in-flow
    const int lb = branch ? (blockIdx.x - nb0) : blockIdx.x;
    const int count = branch ? c1 : c0;
    if (lb * TE >= count) return;
    const int* list            = branch ? list_in : list_out;
    const unsigned short* W1p  = branch ? W1p_in  : W1p_out;
    const float* b1            = branch ? b1_in   : b1_out;
    const unsigned short* W2p  = branch ? W2p_in  : W2p_out;
    const float* b2            = branch ? b2_in   : b2_out;
    const int colbase          = branch ? 0 : OUTD;  // out = concat(flow_in, flow_out)

    const int tid = threadIdx.x;
    if (tid < TE) {
        int idx = lb * TE + tid;
        int e = (idx < count) ? list[idx] : -1;
        s_eid[tid]  = e;
        s_dest[tid] = (e >= 0) ? ei[e] : -1;       // sorted non-decreasing dest rows
        s_col[tid]  = (e >= 0) ? ei[E + e] : 0;
    }
    __syncthreads();

    // Gather msg = concat(xb[col] (bf16), cvt(edge_attr[e])) into LDS. 4 threads/edge.
    {
        const int le  = tid >> 2;
        const int sub = tid & 3;
        const int e   = s_eid[le];
        const ushort8* xrow = reinterpret_cast<const ushort8*>(xb) + (size_t)s_col[le] * (DN / 8);
        #pragma unroll
        for (int j = 0; j < 4; ++j) {
            int seg = sub + j * 4;                       // elems [seg*8, seg*8+8)
            ushort8 v = {0, 0, 0, 0, 0, 0, 0, 0};
            if (e >= 0) v = xrow[seg];
            *reinterpret_cast<ushort8*>(&s_buf[le * MSG_LD + seg * 8]) = v;
        }
        const float4* erow = reinterpret_cast<const float4*>(ea) + (size_t)e * (DE / 4);
        #pragma unroll
        for (int j = 0; j < 4; ++j) {
            float4 v = make_float4(0.f, 0.f, 0.f, 0.f);
            if (e >= 0) v = erow[sub * 4 + j];
            unsigned int lo = cvt_pk2(v.x, v.y);
            unsigned int hi = cvt_pk2(v.z, v.w);
            *reinterpret_cast<uint2*>(&s_buf[le * MSG_LD + DN + sub * 16 + j * 4]) = make_uint2(lo, hi);
        }
    }
    __syncthreads();

    const int wave = tid >> 6;     // 0..3
    const int lane = tid & 63;
    const int ln   = lane & 15;
    const int quad = lane >> 4;

    // ---- GEMM1: h = relu(msg @ W1 + b1).  M=64 (4 m-frags), N=256 (64/wave), K=192.
    f32x4 acc[4][4];
    {
        const int nbase = wave * 64;
        float bias[4];
        #pragma unroll
        for (int t = 0; t < 4; ++t) bias[t] = b1[nbase + t * 16 + ln];
        #pragma unroll
        for (int mt = 0; mt < 4; ++mt)
            #pragma unroll
            for (int t = 0; t < 4; ++t)
                acc[mt][t] = (f32x4){bias[t], bias[t], bias[t], bias[t]};
        #pragma unroll
        for (int kt = 0; kt < DIN / 32; ++kt) {
            short8 a[4], b[4];
            #pragma unroll
            for (int mt = 0; mt < 4; ++mt)
                a[mt] = *reinterpret_cast<const short8*>(
                    &s_buf[(mt * 16 + ln) * MSG_LD + kt * 32 + quad * 8]);
            #pragma unroll
            for (int t = 0; t < 4; ++t)
                b[t] = *reinterpret_cast<const short8*>(
                    &W1p[((kt * HID + nbase + t * 16 + ln) << 5) + quad * 8]);
            #pragma unroll
            for (int mt = 0; mt < 4; ++mt)
                #pragma unroll
                for (int t = 0; t < 4; ++t)
                    acc[mt][t] = __builtin_amdgcn_mfma_f32_16x16x32_bf16(a[mt], b[t], acc[mt][t], 0, 0, 0);
        }
    }
    __syncthreads();   // msg reads done; s_buf re-used for blocked-transposed h

    // ReLU -> bf16 hT in blocked layout: tile (nq = n/4, mb = m/16) holds 4x16
    // row-major bf16 at elem ((nq*NMB + mb)*64 + (n&3)*16 + (m&15)).
    // Lane's 4 rows (m = mt*16 + quad*4 + r) are contiguous -> one cvt_pk pair + one b64 write.
    {
        const int nbase = wave * 64;
        #pragma unroll
        for (int mt = 0; mt < 4; ++mt)
            #pragma unroll
            for (int t = 0; t < 4; ++t) {
                int n = nbase + t * 16 + ln;
                float r0 = acc[mt][t][0], r1 = acc[mt][t][1];
                float r2 = acc[mt][t][2], r3 = acc[mt][t][3];
                r0 = r0 > 0.f ? r0 : 0.f;  r1 = r1 > 0.f ? r1 : 0.f;
                r2 = r2 > 0.f ? r2 : 0.f;  r3 = r3 > 0.f ? r3 : 0.f;
                unsigned int d0 = cvt_pk2(r0, r1);
                unsigned int d1 = cvt_pk2(r2, r3);
                int el = (((n >> 2) * NMB + mt) << 6) + ((n & 3) << 4) + (quad << 2);
                *reinterpret_cast<uint2v*>(&s_buf[el]) = (uint2v){d0, d1};
            }
    }
    __syncthreads();

    // ---- GEMM2: o = h @ W2 + b2.  M=64, N=128 (32/wave), K=256.
    // A-frags via ds_read_b64_tr_b16 from the blocked hT. Lane (ln,quad) needs
    // h[m=mt*16+ln][k=kt*32+quad*8+s]: region (k-block, mt) at byte
    // kt*4096 + quad*1024 + (s>>2)*512 + mt*128; column ln -> per-lane slot ln*8.
    f32x4 acc2[4][2];
    {
        const int nb2 = wave * 32;
        float bz0 = b2[nb2 + ln];
        float bz1 = b2[nb2 + 16 + ln];
        #pragma unroll
        for (int mt = 0; mt < 4; ++mt) {
            acc2[mt][0] = (f32x4){bz0, bz0, bz0, bz0};
            acc2[mt][1] = (f32x4){bz1, bz1, bz1, bz1};
        }
        const unsigned trb = (unsigned)(uintptr_t)(&s_buf[quad * 512 + ln * 4]);
        short8 bn0 = *reinterpret_cast<const short8*>(&W2p[((nb2 + ln) << 5) + quad * 8]);
        short8 bn1 = *reinterpret_cast<const short8*>(&W2p[((nb2 + 16 + ln) << 5) + quad * 8]);

#define G2TR(kt, mt) { \
        uint2v t0 = tr_read<(kt) * 4096 + (mt) * 128>(trb); \
        uint2v t1 = tr_read<(kt) * 4096 + (mt) * 128 + 512>(trb); \
        a[mt] = __builtin_bit_cast(short8, (uint4v){t0.x, t0.y, t1.x, t1.y}); }

#define G2MM(mt) \
        acc2[mt][0] = __builtin_amdgcn_mfma_f32_16x16x32_bf16(a[mt], b0c, acc2[mt][0], 0, 0, 0); \
        acc2[mt][1] = __builtin_amdgcn_mfma_f32_16x16x32_bf16(a[mt], b1c, acc2[mt][1], 0, 0, 0);

#define G2STEP(kt) { \
        short8 a[4]; \
        G2TR(kt, 0) G2TR(kt, 1) G2TR(kt, 2) G2TR(kt, 3) \
        short8 b0c = bn0, b1c = bn1; \
        if ((kt) < 7) { \
            bn0 = *reinterpret_cast<const short8*>(&W2p[((((kt) + 1) * OUTD + nb2 + ln) << 5) + quad * 8]); \
            bn1 = *reinterpret_cast<const short8*>(&W2p[((((kt) + 1) * OUTD + nb2 + 16 + ln) << 5) + quad * 8]); \
        } \
        asm volatile("s_waitcnt lgkmcnt(0)"); \
        __builtin_amdgcn_sched_barrier(0); \
        G2MM(0) G2MM(1) G2MM(2) G2MM(3) }

        G2STEP(0) G2STEP(1) G2STEP(2) G2STEP(3)
        G2STEP(4) G2STEP(5) G2STEP(6) G2STEP(7)
#undef G2STEP
#undef G2MM
#undef G2TR
    }
    __syncthreads();   // hT reads done; s_buf re-used for f32 out tile

    float* s_outf = reinterpret_cast<float*>(s_buf);
    {
        const int nb2 = wave * 32;
        #pragma unroll
        for (int mt = 0; mt < 4; ++mt)
            #pragma unroll
            for (int t = 0; t < 2; ++t)
                #pragma unroll
                for (int r = 0; r < 4; ++r)
                    s_outf[(mt * 16 + quad * 4 + r) * OUT_LD + nb2 + t * 16 + ln] = acc2[mt][t][r];
    }
    __syncthreads();

    // Segment-reduce over sorted dest rows. Runs strictly interior to this
    // thread's row-range are sole-owner (global sort!) -> plain store; boundary -> atomic.
    {
        const int c  = tid & 127;
        const int m0 = (tid >> 7) * 32;
        float run = 0.f;
        int cur = -1, rs = m0;
        for (int m = m0; m < m0 + 32; ++m) {
            int d = s_dest[m];
            float v = s_outf[m * OUT_LD + c];
            if (d != cur) {
                if (cur >= 0) {
                    float* p = &out[(size_t)cur * (2 * OUTD) + colbase + c];
                    if (rs > m0) *p = run; else atomicAdd(p, run);
                }
                cur = d; run = 0.f; rs = m;
            }
            if (d >= 0) run += v;
        }
        if (cur >= 0)
            atomicAdd(&out[(size_t)cur * (2 * OUTD) + colbase + c], run);
    }
}

extern "C" void kernel_launch(void* const* d_in, const int* in_sizes, int n_in,
                              void* d_out, int out_size, void* d_ws, size_t ws_size,
                              hipStream_t stream) {
    const float* x   = (const float*)d_in[0];
    const int*   ei  = (const int*)d_in[1];
    const float* ea  = (const float*)d_in[2];
    const float* W1o = (const float*)d_in[3];
    const float* b1o = (const float*)d_in[4];
    const float* W2o = (const float*)d_in[5];
    const float* b2o = (const float*)d_in[6];
    const float* W1i = (const float*)d_in[7];
    const float* b1i = (const float*)d_in[8];
    const float* W2i = (const float*)d_in[9];
    const float* b2i = (const float*)d_in[10];
    float* out = (float*)d_out;
    const int E = in_sizes[1] / 2;
    const int N = in_sizes[0] / DN;
    const int nch = (N + 1023) >> 10;          // chunks per branch (<=64 assumed)

    // workspace layout
    int* cnt      = (int*)d_ws;                // 2 (+pad to 16)
    int* chunkSum = cnt + 16;                  // 2*nch (<=128)
    int* hist     = chunkSum + 128;            // 2N
    int* cursor   = hist + 2 * (size_t)N;      // 2N
    int* list_out = cursor + 2 * (size_t)N;    // E
    int* list_in  = list_out + E;              // E
    unsigned short* W1po = (unsigned short*)(list_in + E);
    unsigned short* W1pi = W1po + DIN * HID;
    unsigned short* W2po = W1pi + DIN * HID;
    unsigned short* W2pi = W2po + HID * OUTD;
    unsigned short* xb   = W2pi + HID * OUTD;  // N*DN bf16

    hipMemsetAsync(d_out, 0, (size_t)out_size * sizeof(float), stream);
    hipMemsetAsync(d_ws, 0, (576 + 8 * (size_t)N), stream);   // cnt+chunkSum+hist

    const int PACKN = 2 * DIN * HID + 2 * HID * OUTD;
    const int prepN = PACKN + E + N * DN / 8;
    prep_kernel<<<(prepN + 255) / 256, 256, 0, stream>>>(
        W1o, W1i, W2o, W2i, W1po, W1pi, W2po, W2pi, ei, E, N, hist, x, xb);

    scan1_kernel<<<2 * nch, 1024, 0, stream>>>(hist, cursor, chunkSum, N, nch);
    scan2_kernel<<<1, 128, 0, stream>>>(chunkSum, cnt, nch);
    reorder_kernel<<<(E + 255) / 256, 256, 0, stream>>>(
        ei, E, N, nch, cursor, chunkSum, list_out, list_in);

    const int nblk = (E + TE - 1) / TE + 2;    // device-side branch split via cnt[]
    mlp_scatter_kernel<<<nblk, NT, 0, stream>>>(
        xb, ei, ea, W1po, W1pi, b1o, b1i, W2po, W2pi, b2o, b2i,
        list_out, list_in, cnt, out, E);
}